// Round 1
// baseline (294.167 us; speedup 1.0000x reference)
//
#include <hip/hip_runtime.h>
#include <hip/hip_bf16.h>

// ElasticMLP fused: 8 layers, H=128, B=262144, relu each layer, skip(+x) for l>0.
// out[b,j] = relu(sum_i h[b,i]*w[l][j,i] + b[l][j]) (+ x[b,j] if l>0)
//
// Strategy: bf16 MFMA (16x16x32), h tile resident in LDS across all 8 layers,
// per-layer W staged to LDS from a bf16 copy pre-converted into d_ws.
// x kept in fp32 registers (C-fragment layout) for exact skip-adds.

typedef __bf16 bf16_t;
typedef __bf16 bf16x8 __attribute__((ext_vector_type(8)));
typedef float floatx4 __attribute__((ext_vector_type(4)));

#define HID 128
#define NLAYERS 8
#define TM 128          // rows per block
#define LDH 136         // padded LDS row stride in bf16 elems (+8 => 2-way-free banks)

__global__ __launch_bounds__(256) void wconv_kernel(const float* __restrict__ w,
                                                    bf16_t* __restrict__ wb) {
    int i = blockIdx.x * 256 + threadIdx.x;   // 8*128*128 = 131072 elems
    wb[i] = (bf16_t)w[i];
}

__global__ __launch_bounds__(256, 2) void mlp_kernel(
    const float* __restrict__ x, const bf16_t* __restrict__ wb,
    const float* __restrict__ bias, float* __restrict__ out)
{
    __shared__ __align__(16) bf16_t hs[TM][LDH];    // activations (bf16)
    __shared__ __align__(16) bf16_t wsh[HID][LDH];  // current layer weights
    __shared__ float bs[HID];

    const int tid  = threadIdx.x;
    const int wave = tid >> 6;
    const int lane = tid & 63;
    const int c16  = lane & 15;        // col-in-16 (C/D + B frag) / row-in-16 (A frag)
    const int quad = lane >> 4;        // k-offset group / row group in C
    const int m0 = (wave >> 1) * 64;   // wave quadrant within 128x128 tile
    const int n0 = (wave & 1) * 64;
    const long rowbase = (long)blockIdx.x * TM;

    // --- x in registers, C-fragment layout: xr[mi][ni][r] = x[row][col],
    //     row = m0+mi*16+quad*4+r, col = n0+ni*16+c16. Covers tile exactly once
    //     across the block; 16-lane-contiguous cols => 64B coalesced chunks.
    float xr[4][4][4];
#pragma unroll
    for (int mi = 0; mi < 4; ++mi)
#pragma unroll
      for (int r = 0; r < 4; ++r) {
        const float* xrow = x + (rowbase + m0 + mi*16 + quad*4 + r) * HID;
#pragma unroll
        for (int ni = 0; ni < 4; ++ni)
          xr[mi][ni][r] = xrow[n0 + ni*16 + c16];
      }

    // --- h_0 = bf16(x) into LDS
#pragma unroll
    for (int mi = 0; mi < 4; ++mi)
#pragma unroll
      for (int ni = 0; ni < 4; ++ni)
#pragma unroll
        for (int r = 0; r < 4; ++r)
          hs[m0 + mi*16 + quad*4 + r][n0 + ni*16 + c16] = (bf16_t)xr[mi][ni][r];

    // --- prefetch layer-0 weights into registers (8 x 16B per thread = 32 KB/block)
    const bf16x8* wbv = (const bf16x8*)wb;   // 2048 chunks per layer
    bf16x8 wreg[8];
#pragma unroll
    for (int p = 0; p < 8; ++p) wreg[p] = wbv[p*256 + tid];
    float breg = (tid < HID) ? bias[tid] : 0.0f;

    for (int l = 0; l < NLAYERS; ++l) {
        __syncthreads();   // hs writes (prev layer) + wsh frag reads (prev layer) done
        // stage W_l from registers -> LDS
#pragma unroll
        for (int p = 0; p < 8; ++p) {
            int f = p*256 + tid;                    // chunk id; 16 chunks per row
            *(bf16x8*)&wsh[f >> 4][(f & 15)*8] = wreg[p];
        }
        if (tid < HID) bs[tid] = breg;
        __syncthreads();

        // prefetch next layer's weights during this layer's MFMAs (independent of hs)
        if (l + 1 < NLAYERS) {
#pragma unroll
            for (int p = 0; p < 8; ++p) wreg[p] = wbv[(l+1)*2048 + p*256 + tid];
            if (tid < HID) breg = bias[(l+1)*HID + tid];
        }

        floatx4 acc[4][4];
#pragma unroll
        for (int mi = 0; mi < 4; ++mi)
#pragma unroll
          for (int ni = 0; ni < 4; ++ni)
            acc[mi][ni] = (floatx4)0.0f;

        // K = 128 in 4 steps of 32
#pragma unroll
        for (int k = 0; k < 4; ++k) {
            const int kc = k*32 + quad*8;
            bf16x8 af[4], bfr[4];
#pragma unroll
            for (int mi = 0; mi < 4; ++mi)
                af[mi] = *(const bf16x8*)&hs[m0 + mi*16 + c16][kc];
#pragma unroll
            for (int ni = 0; ni < 4; ++ni)
                bfr[ni] = *(const bf16x8*)&wsh[n0 + ni*16 + c16][kc];
#pragma unroll
            for (int mi = 0; mi < 4; ++mi)
#pragma unroll
              for (int ni = 0; ni < 4; ++ni)
                acc[mi][ni] = __builtin_amdgcn_mfma_f32_16x16x32_bf16(
                                  af[mi], bfr[ni], acc[mi][ni], 0, 0, 0);
        }

        float bv[4];
#pragma unroll
        for (int ni = 0; ni < 4; ++ni) bv[ni] = bs[n0 + ni*16 + c16];

        if (l < NLAYERS - 1) {
            __syncthreads();   // all frag reads of hs done before overwrite
#pragma unroll
            for (int mi = 0; mi < 4; ++mi)
#pragma unroll
              for (int ni = 0; ni < 4; ++ni)
#pragma unroll
                for (int r = 0; r < 4; ++r) {
                    float v = acc[mi][ni][r] + bv[ni];
                    v = fmaxf(v, 0.0f);
                    if (l > 0) v += xr[mi][ni][r];
                    hs[m0 + mi*16 + quad*4 + r][n0 + ni*16 + c16] = (bf16_t)v;
                }
        } else {
            // last layer: relu + skip, store fp32 to global
#pragma unroll
            for (int mi = 0; mi < 4; ++mi)
#pragma unroll
              for (int r = 0; r < 4; ++r) {
                float* orow = out + (rowbase + m0 + mi*16 + quad*4 + r) * HID;
#pragma unroll
                for (int ni = 0; ni < 4; ++ni) {
                    float v = acc[mi][ni][r] + bv[ni];
                    v = fmaxf(v, 0.0f);
                    v += xr[mi][ni][r];
                    orow[n0 + ni*16 + c16] = v;
                }
              }
        }
    }
}

extern "C" void kernel_launch(void* const* d_in, const int* in_sizes, int n_in,
                              void* d_out, int out_size, void* d_ws, size_t ws_size,
                              hipStream_t stream) {
    const float* x = (const float*)d_in[0];    // 262144*128
    const float* w = (const float*)d_in[1];    // 8*128*128
    const float* b = (const float*)d_in[2];    // 8*128
    float* out = (float*)d_out;
    bf16_t* wb = (bf16_t*)d_ws;                // 131072 bf16 = 256 KB scratch

    // convert weights fp32 -> bf16 once per launch (ws re-poisoned each call)
    wconv_kernel<<<NLAYERS*HID*HID/256, 256, 0, stream>>>(w, wb);

    const int nblocks = 262144 / TM;           // 2048
    mlp_kernel<<<nblocks, 256, 0, stream>>>(x, wb, b, out);
}

// Round 2
// 288.701 us; speedup vs baseline: 1.0189x; 1.0189x over previous
//
#include <hip/hip_runtime.h>
#include <hip/hip_bf16.h>

// ElasticMLP fused: 8 layers, H=128, B=262144, relu each layer, skip(+x) for l>0.
//
// Round-2 structure: transposed MFMA roles. A = W (m = neuron), B = h (n = batch),
// so C gives each lane 4 CONSECUTIVE NEURONS of one batch row:
//   - h writeback = ds_write_b64 (16/thread) instead of 64x ds_write_b16
//   - x loads / out stores = dwordx4
// Bias folded into acc init (constant along N). 2 barriers/layer.

typedef __bf16 bf16_t;
typedef __bf16 bf16x8 __attribute__((ext_vector_type(8)));
typedef __bf16 bf16x4 __attribute__((ext_vector_type(4)));
typedef float floatx4 __attribute__((ext_vector_type(4)));

#define HID 128
#define NLAYERS 8
#define TM 128          // batch rows per block
#define LDH 136         // LDS row stride (bf16 elems). 272B: keeps 16B alignment,
                        // frag b128 reads & b64 writes are bank-floor-optimal.

__global__ __launch_bounds__(256) void wconv_kernel(const float* __restrict__ w,
                                                    bf16_t* __restrict__ wb) {
    int i = (blockIdx.x * 256 + threadIdx.x) * 4;   // 131072 elems / 4 => 128 blocks
    floatx4 v = *(const floatx4*)&w[i];
    bf16x4 o = { (bf16_t)v[0], (bf16_t)v[1], (bf16_t)v[2], (bf16_t)v[3] };
    *(bf16x4*)&wb[i] = o;
}

__global__ __launch_bounds__(256, 2) void mlp_kernel(
    const float* __restrict__ x, const bf16_t* __restrict__ wb,
    const float* __restrict__ bias, float* __restrict__ out)
{
    __shared__ __align__(16) bf16_t hs[TM][LDH];    // activations [batch][i]
    __shared__ __align__(16) bf16_t wsh[HID][LDH];  // current layer W [j][i]

    const int tid  = threadIdx.x;
    const int wave = tid >> 6;
    const int lane = tid & 63;
    const int c16  = lane & 15;        // A/B frag row index; C col (batch)
    const int quad = lane >> 4;        // k-group; C row group (neuron)
    const int m0 = (wave >> 1) * 64;   // neuron offset of wave quadrant
    const int n0 = (wave & 1) * 64;    // batch offset of wave quadrant
    const long rowbase = (long)blockIdx.x * TM;
    const int jb = m0 + quad * 4;      // neuron base for this lane (+ mi*16)

    // --- x in C-fragment layout: xr[mi][ni] = x[batch=n0+ni*16+c16][jb+mi*16 .. +3]
    floatx4 xr[4][4];
#pragma unroll
    for (int ni = 0; ni < 4; ++ni) {
        const float* xrow = x + (rowbase + n0 + ni*16 + c16) * HID;
#pragma unroll
        for (int mi = 0; mi < 4; ++mi)
            xr[mi][ni] = *(const floatx4*)&xrow[jb + mi*16];
    }
    // --- h0 = bf16(x): 4 consecutive neurons per write => ds_write_b64
#pragma unroll
    for (int ni = 0; ni < 4; ++ni) {
        bf16_t* hrow = &hs[n0 + ni*16 + c16][0];
#pragma unroll
        for (int mi = 0; mi < 4; ++mi) {
            floatx4 v = xr[mi][ni];
            bf16x4 o = { (bf16_t)v[0], (bf16_t)v[1], (bf16_t)v[2], (bf16_t)v[3] };
            *(bf16x4*)&hrow[jb + mi*16] = o;
        }
    }

    // --- prefetch layer-0 weights (regs) + bias frags
    const bf16x8* wbv = (const bf16x8*)wb;   // 2048 16B-chunks per layer
    bf16x8 wreg[8];
#pragma unroll
    for (int p = 0; p < 8; ++p) wreg[p] = wbv[p*256 + tid];
    floatx4 bnext[4];
#pragma unroll
    for (int mi = 0; mi < 4; ++mi) bnext[mi] = *(const floatx4*)&bias[jb + mi*16];

    for (int l = 0; l < NLAYERS; ++l) {
        // stage W_l regs -> LDS (prev layer's reads fenced by the post-read sync)
#pragma unroll
        for (int p = 0; p < 8; ++p) {
            int f = p*256 + tid;                    // 16 chunks per W row
            *(bf16x8*)&wsh[f >> 4][(f & 15) * 8] = wreg[p];
        }
        __syncthreads();   // wsh staged; hs(l) writes visible

        // acc init = bias (before bnext is overwritten by the prefetch)
        floatx4 acc[4][4];
#pragma unroll
        for (int mi = 0; mi < 4; ++mi)
#pragma unroll
          for (int ni = 0; ni < 4; ++ni)
            acc[mi][ni] = bnext[mi];

        // prefetch next layer's W + bias during this layer's MFMAs
        if (l + 1 < NLAYERS) {
#pragma unroll
            for (int p = 0; p < 8; ++p) wreg[p] = wbv[(l+1)*2048 + p*256 + tid];
#pragma unroll
            for (int mi = 0; mi < 4; ++mi)
                bnext[mi] = *(const floatx4*)&bias[(l+1)*HID + jb + mi*16];
        }

        // K = 128 in 4 steps of 32
#pragma unroll
        for (int k = 0; k < 4; ++k) {
            const int kc = k*32 + quad*8;
            bf16x8 af[4], bf[4];
#pragma unroll
            for (int mi = 0; mi < 4; ++mi)
                af[mi] = *(const bf16x8*)&wsh[m0 + mi*16 + c16][kc];   // A = W
#pragma unroll
            for (int ni = 0; ni < 4; ++ni)
                bf[ni] = *(const bf16x8*)&hs[n0 + ni*16 + c16][kc];    // B = h
#pragma unroll
            for (int mi = 0; mi < 4; ++mi)
#pragma unroll
              for (int ni = 0; ni < 4; ++ni)
                acc[mi][ni] = __builtin_amdgcn_mfma_f32_16x16x32_bf16(
                                  af[mi], bf[ni], acc[mi][ni], 0, 0, 0);
        }
        __syncthreads();   // all hs/wsh frag reads done

        if (l < NLAYERS - 1) {
            // h' = relu(acc) (+x for l>0), packed b64 writes
#pragma unroll
            for (int ni = 0; ni < 4; ++ni) {
                bf16_t* hrow = &hs[n0 + ni*16 + c16][0];
#pragma unroll
                for (int mi = 0; mi < 4; ++mi) {
                    floatx4 v = acc[mi][ni];
                    float s0 = fmaxf(v[0], 0.0f), s1 = fmaxf(v[1], 0.0f);
                    float s2 = fmaxf(v[2], 0.0f), s3 = fmaxf(v[3], 0.0f);
                    if (l > 0) {
                        floatx4 xv = xr[mi][ni];
                        s0 += xv[0]; s1 += xv[1]; s2 += xv[2]; s3 += xv[3];
                    }
                    bf16x4 o = { (bf16_t)s0, (bf16_t)s1, (bf16_t)s2, (bf16_t)s3 };
                    *(bf16x4*)&hrow[jb + mi*16] = o;
                }
            }
        } else {
            // last layer: relu + skip, fp32 dwordx4 stores
#pragma unroll
            for (int ni = 0; ni < 4; ++ni) {
                float* orow = out + (rowbase + n0 + ni*16 + c16) * HID;
#pragma unroll
                for (int mi = 0; mi < 4; ++mi) {
                    floatx4 v = acc[mi][ni];
                    floatx4 xv = xr[mi][ni];
                    floatx4 o;
                    o[0] = fmaxf(v[0], 0.0f) + xv[0];
                    o[1] = fmaxf(v[1], 0.0f) + xv[1];
                    o[2] = fmaxf(v[2], 0.0f) + xv[2];
                    o[3] = fmaxf(v[3], 0.0f) + xv[3];
                    *(floatx4*)&orow[jb + mi*16] = o;
                }
            }
        }
    }
}

extern "C" void kernel_launch(void* const* d_in, const int* in_sizes, int n_in,
                              void* d_out, int out_size, void* d_ws, size_t ws_size,
                              hipStream_t stream) {
    const float* x = (const float*)d_in[0];    // 262144*128
    const float* w = (const float*)d_in[1];    // 8*128*128
    const float* b = (const float*)d_in[2];    // 8*128
    float* out = (float*)d_out;
    bf16_t* wb = (bf16_t*)d_ws;                // 131072 bf16 = 256 KB scratch

    wconv_kernel<<<NLAYERS*HID*HID/(256*4), 256, 0, stream>>>(w, wb);

    const int nblocks = 262144 / TM;           // 2048
    mlp_kernel<<<nblocks, 256, 0, stream>>>(x, wb, b, out);
}